// Round 6
// baseline (690.493 us; speedup 1.0000x reference)
//
#include <hip/hip_runtime.h>
#include <hip/hip_bf16.h>

// ---------------- problem constants ----------------
#define NTOK 768
#define DT   447
#define CS   384
#define TFD  831          // 447+384
#define TFDP 832          // padded K for MFMA (26*32)
#define CZ   128
#define RELD 139
#define NCOL 640          // 384 (s_init) + 128 (a) + 128 (b)

// d_out offsets (in floats)
#define OFF_SINIT  (NTOK*TFD)                    // 638208
#define OFF_Z      (OFF_SINIT + NTOK*CS)         // 933120
#define OFF_REL    (OFF_Z + NTOK*NTOK*CZ)        // 76430592

// ws byte offsets (all 16B aligned)
#define WSB_A    0                // 768*128 f32   = 393216 B
#define WSB_B    393216           // 768*128 f32
#define WSB_WPT  786432           // 139*128 bf16  = 35584 B
#define WSB_SB   822016           // 768*832 bf16  = 1277952 B
#define WSB_WB   2099968          // 640*832 bf16  = 1064960 B

using short8 = __attribute__((ext_vector_type(8))) short;
using f32x4  = __attribute__((ext_vector_type(4))) float;
using u32x2  = __attribute__((ext_vector_type(2))) unsigned int;

__device__ __forceinline__ unsigned short f2bf(float v) {
    __hip_bfloat16 h = __float2bfloat16(v);
    return *reinterpret_cast<unsigned short*>(&h);
}
__device__ __forceinline__ float bf_lo(unsigned u) { return __uint_as_float(u << 16); }
__device__ __forceinline__ float bf_hi(unsigned u) { return __uint_as_float(u & 0xffff0000u); }

// pk = rd | (td+66)<<8 | (cd+133)<<16 | se<<24   (shared by z/rel kernels)
__device__ __forceinline__ int make_pk(int i, int j,
                                       const int* __restrict__ tok, const int* __restrict__ res,
                                       const int* __restrict__ asym, const int* __restrict__ ent,
                                       const int* __restrict__ sym) {
    int ti = tok[i], ri = res[i], ai = asym[i], ei = ent[i], si = sym[i];
    int tj = tok[j], rj = res[j], aj = asym[j], ej = ent[j], sj = sym[j];
    int sc = (ai == aj);
    int sr = (ri == rj);
    int se = (ei == ej);
    int rd = sc ? min(max(ri - rj + 32, 0), 64) : 65;
    int td = ((sc & sr) ? min(max(ti - tj + 32, 0), 64) : 65) + 66;
    int cd = (se ? min(max(si - sj + 2, 0), 4) : 5) + 133;
    return rd | (td << 8) | (cd << 16) | (se << 24);
}

// ---------------- kernel 1: concat + bf16 copies + W_pos transpose ----------------
#define PREP_TOTAL 1189248
__launch_bounds__(256)
__global__ void prep_kernel(const float* __restrict__ tf, const float* __restrict__ ta,
                            const float* __restrict__ Wsingle, const float* __restrict__ Wleft,
                            const float* __restrict__ Wright, const float* __restrict__ wpos,
                            float* __restrict__ s_input, short* __restrict__ Sb,
                            short* __restrict__ Wb, unsigned short* __restrict__ wpt) {
    int idx = blockIdx.x * 256 + threadIdx.x;
    if (idx < NTOK * TFD) {
        int n = idx / TFD;
        int d = idx - n * TFD;
        float v = (d < DT) ? tf[n * DT + d] : ta[n * CS + (d - DT)];
        s_input[idx] = v;
        Sb[n * TFDP + d] = (short)f2bf(v);
    } else if (idx < NTOK * TFD + NTOK) {
        int n = idx - NTOK * TFD;
        Sb[n * TFDP + TFD] = 0;            // K pad
    } else if (idx < NTOK * TFD + NTOK + NCOL * TFDP) {
        int t = idx - (NTOK * TFD + NTOK);
        int c = t / TFDP;
        int d = t - c * TFDP;
        float v;
        if (d >= TFD)       v = 0.f;       // K pad
        else if (c < 384)   v = Wsingle[c * TFD + d];
        else if (c < 512)   v = Wleft[(c - 384) * TFD + d];
        else                v = Wright[(c - 512) * TFD + d];
        Wb[t] = (short)f2bf(v);
    } else {
        int t = idx - (NTOK * TFD + NTOK + NCOL * TFDP);
        if (t < RELD * CZ) {
            int r = t >> 7;                 // / 128
            int c = t & 127;
            wpt[t] = f2bf(wpos[c * RELD + r]);   // transpose to (r, c)
        }
    }
}

// ---------------- kernel 2: bf16 MFMA GEMM (one 16x16 tile per wave) ----------------
__launch_bounds__(256)
__global__ void mfma_gemm_kernel(const short* __restrict__ Sb, const short* __restrict__ Wb,
                                 float* __restrict__ s_init, float* __restrict__ a_out,
                                 float* __restrict__ b_out) {
    int tid  = threadIdx.x;
    int lane = tid & 63;
    int wv   = tid >> 6;
    int m0 = blockIdx.x * 16;              // 0..47 tiles
    int n0 = (blockIdx.y * 4 + wv) * 16;   // 0..39 tiles
    int fr   = lane & 15;                  // fragment row (m for A, n for B)
    int koff = (lane >> 4) * 8;            // quad * 8

    const short* ap = Sb + (m0 + fr) * TFDP + koff;
    const short* bp = Wb + (n0 + fr) * TFDP + koff;
    f32x4 acc = {0.f, 0.f, 0.f, 0.f};
    #pragma unroll
    for (int k = 0; k < TFDP; k += 32) {
        short8 af = *reinterpret_cast<const short8*>(ap + k);
        short8 bf = *reinterpret_cast<const short8*>(bp + k);
        acc = __builtin_amdgcn_mfma_f32_16x16x32_bf16(af, bf, acc, 0, 0, 0);
    }
    float* dst; int ldc, c0;
    if (n0 < 384)      { dst = s_init; ldc = 384; c0 = n0; }
    else if (n0 < 512) { dst = a_out;  ldc = 128; c0 = n0 - 384; }
    else               { dst = b_out;  ldc = 128; c0 = n0 - 512; }
    int col = lane & 15;
    int r0  = (lane >> 4) * 4;             // C/D: col=lane&15, row=(lane>>4)*4+reg  [m89/m91]
    #pragma unroll
    for (int r = 0; r < 4; ++r)
        dst[(m0 + r0 + r) * ldc + c0 + col] = acc[r];
}

// ---------------- kernel 3a: z writer (load-heavy, occupancy-pinned 6 waves/EU) ----------------
// grid (768, 3), block 256.
__launch_bounds__(256, 6)
__global__ void z_kernel(const float* __restrict__ a_in, const float* __restrict__ b_in,
                         const unsigned short* __restrict__ wpt_g,
                         const float* __restrict__ wbond, const float* __restrict__ contact,
                         const int* __restrict__ tok, const int* __restrict__ res,
                         const int* __restrict__ asym, const int* __restrict__ ent,
                         const int* __restrict__ sym,
                         float* __restrict__ z_out) {
    __shared__ int   pkS[256];
    __shared__ float cfS[256];

    int tid = threadIdx.x;
    int i   = blockIdx.x;
    int j0  = blockIdx.y * 256;
    int c    = (tid & 31) * 4;
    int jrow = tid >> 5;

    // per-lane constants (global, L2-hit)
    f32x4 av  = *reinterpret_cast<const f32x4*>(&a_in[i * CZ + c]);
    f32x4 wbv = *reinterpret_cast<const f32x4*>(&wbond[c]);
    u32x2 us  = *reinterpret_cast<const u32x2*>(&wpt_g[132 * CZ + c]);

    pkS[tid] = make_pk(i, j0 + tid, tok, res, asym, ent, sym);
    cfS[tid] = contact[i * NTOK + j0 + tid];
    __syncthreads();

    float wse0 = bf_lo(us.x), wse1 = bf_hi(us.x), wse2 = bf_lo(us.y), wse3 = bf_hi(us.y);
    size_t zbase = ((size_t)(i * NTOK + j0)) * CZ;

    #pragma unroll 2
    for (int it = 0; it < 32; ++it) {
        int jj = jrow + it * 8;
        int pk = pkS[jj];
        float cf = cfS[jj];
        float pse = (float)((unsigned)pk >> 24);
        int p1 = (pk & 255) * CZ + c;
        int p2 = ((pk >> 8) & 255) * CZ + c;
        int p3 = ((pk >> 16) & 255) * CZ + c;
        f32x4 bv = *reinterpret_cast<const f32x4*>(&b_in[(j0 + jj) * CZ + c]);
        u32x2 u1 = *reinterpret_cast<const u32x2*>(&wpt_g[p1]);
        u32x2 u2 = *reinterpret_cast<const u32x2*>(&wpt_g[p2]);
        u32x2 u3 = *reinterpret_cast<const u32x2*>(&wpt_g[p3]);
        f32x4 z;
        z.x = av.x + bv.x + bf_lo(u1.x) + bf_lo(u2.x) + bf_lo(u3.x) + pse * wse0 + cf * wbv.x;
        z.y = av.y + bv.y + bf_hi(u1.x) + bf_hi(u2.x) + bf_hi(u3.x) + pse * wse1 + cf * wbv.y;
        z.z = av.z + bv.z + bf_lo(u1.y) + bf_lo(u2.y) + bf_lo(u3.y) + pse * wse2 + cf * wbv.z;
        z.w = av.w + bv.w + bf_hi(u1.y) + bf_hi(u2.y) + bf_hi(u3.y) + pse * wse3 + cf * wbv.w;
        *reinterpret_cast<f32x4*>(&z_out[zbase + (size_t)(jj * CZ + c)]) = z;
    }
}

// ---------------- kernel 3b: rel writer (VALU-decode, low VGPR, 8 waves/EU) ----------------
// grid (768, 3), block 256. Flat f32x4 stream with exact magic-div (j,r) decode.
__launch_bounds__(256, 8)
__global__ void rel_kernel(const int* __restrict__ tok, const int* __restrict__ res,
                           const int* __restrict__ asym, const int* __restrict__ ent,
                           const int* __restrict__ sym,
                           float* __restrict__ rel_out) {
    __shared__ int pkS[256];

    int tid = threadIdx.x;
    int i   = blockIdx.x;
    int j0  = blockIdx.y * 256;

    pkS[tid] = make_pk(i, j0 + tid, tok, res, asym, ent, sym);
    __syncthreads();

    // 256*139 = 35584 floats = 8896 aligned f32x4, flat stream.
    size_t rbase = ((size_t)(i * NTOK + j0)) * RELD;
    for (int f = tid; f < (256 * RELD) / 4; f += 256) {
        int e = f * 4;
        float v[4];
        #pragma unroll
        for (int k = 0; k < 4; ++k) {
            int ek = e + k;
            // exact j = ek/139 for ek < 35584:  (ek*482798) >> 26, via umulhi(ek<<6, M)
            int j = (int)__umulhi((unsigned)(ek << 6), 482798u);
            int r = ek - j * 139;
            int pk = pkS[j];
            int hit = (r == (pk & 255)) | (r == ((pk >> 8) & 255)) | (r == ((pk >> 16) & 255));
            float pse = (float)((unsigned)pk >> 24);
            v[k] = hit ? 1.0f : ((r == 132) ? pse : 0.0f);
        }
        f32x4 vv = {v[0], v[1], v[2], v[3]};
        *reinterpret_cast<f32x4*>(&rel_out[rbase + (size_t)e]) = vv;
    }
}

// ---------------- launcher ----------------
extern "C" void kernel_launch(void* const* d_in, const int* in_sizes, int n_in,
                              void* d_out, int out_size, void* d_ws, size_t ws_size,
                              hipStream_t stream) {
    const float* tf      = (const float*)d_in[0];
    const float* ta      = (const float*)d_in[1];
    const float* contact = (const float*)d_in[2];
    const int*   tok     = (const int*)d_in[3];
    const int*   res     = (const int*)d_in[4];
    const int*   asym    = (const int*)d_in[5];
    const int*   ent     = (const int*)d_in[6];
    const int*   sym     = (const int*)d_in[7];
    const float* Wsingle = (const float*)d_in[8];
    const float* Wleft   = (const float*)d_in[9];
    const float* Wright  = (const float*)d_in[10];
    const float* Wpos    = (const float*)d_in[11];
    const float* Wbond   = (const float*)d_in[12];

    float* out     = (float*)d_out;
    float* s_input = out;
    float* s_init  = out + OFF_SINIT;
    float* z       = out + OFF_Z;
    float* rel     = out + OFF_REL;

    char* wsb = (char*)d_ws;
    float*          a_ws = (float*)(wsb + WSB_A);
    float*          b_ws = (float*)(wsb + WSB_B);
    unsigned short* wpt  = (unsigned short*)(wsb + WSB_WPT);
    short*          Sb   = (short*)(wsb + WSB_SB);
    short*          Wb   = (short*)(wsb + WSB_WB);

    prep_kernel<<<(PREP_TOTAL + 255) / 256, 256, 0, stream>>>(
        tf, ta, Wsingle, Wleft, Wright, Wpos, s_input, Sb, Wb, wpt);

    mfma_gemm_kernel<<<dim3(48, 10), 256, 0, stream>>>(Sb, Wb, s_init, a_ws, b_ws);

    z_kernel<<<dim3(768, 3), 256, 0, stream>>>(
        a_ws, b_ws, wpt, Wbond, contact, tok, res, asym, ent, sym, z);

    rel_kernel<<<dim3(768, 3), 256, 0, stream>>>(
        tok, res, asym, ent, sym, rel);
}

// Round 7
// 668.908 us; speedup vs baseline: 1.0323x; 1.0323x over previous
//
#include <hip/hip_runtime.h>
#include <hip/hip_bf16.h>

// ---------------- problem constants ----------------
#define NTOK 768
#define DT   447
#define CS   384
#define TFD  831          // 447+384
#define TFDP 832          // padded K for MFMA (26*32)
#define CZ   128
#define RELD 139
#define NCOL 640          // 384 (s_init) + 128 (a) + 128 (b)
#define KBLK 26           // 832/32
#define FRAG_STRIDE 512   // shorts per (blk,kblk) fragment group: 4q*16fr*8e

// d_out offsets (in floats)
#define OFF_SINIT  (NTOK*TFD)                    // 638208
#define OFF_Z      (OFF_SINIT + NTOK*CS)         // 933120
#define OFF_REL    (OFF_Z + NTOK*NTOK*CZ)        // 76430592

// ws byte offsets (all 16B aligned)
#define WSB_A    0                // 768*128 f32   = 393216 B
#define WSB_B    393216           // 768*128 f32
#define WSB_WPT  786432           // 139*128 bf16  = 35584 B
#define WSB_SB   822016           // 768*832 bf16  = 1277952 B (fragment-major)
#define WSB_WB   2099968          // 640*832 bf16  = 1064960 B (fragment-major)

using short8 = __attribute__((ext_vector_type(8))) short;
using f32x4  = __attribute__((ext_vector_type(4))) float;
using u32x2  = __attribute__((ext_vector_type(2))) unsigned int;

__device__ __forceinline__ unsigned short f2bf(float v) {
    __hip_bfloat16 h = __float2bfloat16(v);
    return *reinterpret_cast<unsigned short*>(&h);
}
__device__ __forceinline__ float bf_lo(unsigned u) { return __uint_as_float(u << 16); }
__device__ __forceinline__ float bf_hi(unsigned u) { return __uint_as_float(u & 0xffff0000u); }

// fragment-major offset for row-block structure: row n (or col c), depth d
// layout dims: [blk][kblk=26][q=4][fr=16][e=8]
__device__ __forceinline__ int frag_off(int n, int d) {
    return ((((n >> 4) * KBLK + (d >> 5)) * 4 + ((d >> 3) & 3)) * 16 + (n & 15)) * 8 + (d & 7);
}

// pk = rd | (td+66)<<8 | (cd+133)<<16 | se<<24
__device__ __forceinline__ int make_pk(int i, int j,
                                       const int* __restrict__ tok, const int* __restrict__ res,
                                       const int* __restrict__ asym, const int* __restrict__ ent,
                                       const int* __restrict__ sym) {
    int ti = tok[i], ri = res[i], ai = asym[i], ei = ent[i], si = sym[i];
    int tj = tok[j], rj = res[j], aj = asym[j], ej = ent[j], sj = sym[j];
    int sc = (ai == aj);
    int sr = (ri == rj);
    int se = (ei == ej);
    int rd = sc ? min(max(ri - rj + 32, 0), 64) : 65;
    int td = ((sc & sr) ? min(max(ti - tj + 32, 0), 64) : 65) + 66;
    int cd = (se ? min(max(si - sj + 2, 0), 4) : 5) + 133;
    return rd | (td << 8) | (cd << 16) | (se << 24);
}

// ---------------- kernel 1: concat + bf16 fragment-major scatter + W_pos transpose ----------------
// ranges: [0,638208) concat+Sb | [638208,638976) Sb pad | [638976,1171456) Wb | [1171456,1189248) wpt
#define PREP_TOTAL 1189248
__launch_bounds__(256)
__global__ void prep_kernel(const float* __restrict__ tf, const float* __restrict__ ta,
                            const float* __restrict__ Wsingle, const float* __restrict__ Wleft,
                            const float* __restrict__ Wright, const float* __restrict__ wpos,
                            float* __restrict__ s_input, short* __restrict__ Sb,
                            short* __restrict__ Wb, unsigned short* __restrict__ wpt) {
    int idx = blockIdx.x * 256 + threadIdx.x;
    if (idx < NTOK * TFD) {
        int n = idx / TFD;
        int d = idx - n * TFD;
        float v = (d < DT) ? tf[n * DT + d] : ta[n * CS + (d - DT)];
        s_input[idx] = v;
        Sb[frag_off(n, d)] = (short)f2bf(v);
    } else if (idx < NTOK * TFD + NTOK) {
        int n = idx - NTOK * TFD;
        Sb[frag_off(n, TFD)] = 0;          // K pad (d=831)
    } else if (idx < NTOK * TFD + NTOK + NCOL * TFDP) {
        int t = idx - (NTOK * TFD + NTOK);
        int c = t / TFDP;
        int d = t - c * TFDP;
        float v;
        if (d >= TFD)       v = 0.f;       // K pad
        else if (c < 384)   v = Wsingle[c * TFD + d];
        else if (c < 512)   v = Wleft[(c - 384) * TFD + d];
        else                v = Wright[(c - 512) * TFD + d];
        Wb[frag_off(c, d)] = (short)f2bf(v);
    } else {
        int t = idx - (NTOK * TFD + NTOK + NCOL * TFDP);
        if (t < RELD * CZ) {
            int r = t >> 7;                 // / 128
            int c = t & 127;
            wpt[t] = f2bf(wpos[c * RELD + r]);   // transpose to (r, c)
        }
    }
}

// ---------------- kernel 2: bf16 MFMA GEMM, fragment-major coalesced loads ----------------
// Per (blk,kblk) group the wave's fragment is exactly shorts [lane*8 .. lane*8+8) —
// each load instruction covers one contiguous 1 KB block (perfect coalescing).
__launch_bounds__(256)
__global__ void mfma_gemm_kernel(const short* __restrict__ Sb, const short* __restrict__ Wb,
                                 float* __restrict__ s_init, float* __restrict__ a_out,
                                 float* __restrict__ b_out) {
    int tid  = threadIdx.x;
    int lane = tid & 63;
    int wv   = tid >> 6;
    int mb = blockIdx.x;                   // 0..47 row-blocks
    int nb = blockIdx.y * 4 + wv;          // 0..39 col-blocks

    const short* ap = Sb + mb * (KBLK * FRAG_STRIDE) + lane * 8;
    const short* bp = Wb + nb * (KBLK * FRAG_STRIDE) + lane * 8;
    f32x4 acc = {0.f, 0.f, 0.f, 0.f};
    #pragma unroll
    for (int kk = 0; kk < KBLK; ++kk) {
        short8 af = *reinterpret_cast<const short8*>(ap + kk * FRAG_STRIDE);
        short8 bf = *reinterpret_cast<const short8*>(bp + kk * FRAG_STRIDE);
        acc = __builtin_amdgcn_mfma_f32_16x16x32_bf16(af, bf, acc, 0, 0, 0);
    }
    int m0 = mb * 16, n0 = nb * 16;
    float* dst; int ldc, c0;
    if (n0 < 384)      { dst = s_init; ldc = 384; c0 = n0; }
    else if (n0 < 512) { dst = a_out;  ldc = 128; c0 = n0 - 384; }
    else               { dst = b_out;  ldc = 128; c0 = n0 - 512; }
    int col = lane & 15;
    int r0  = (lane >> 4) * 4;             // C/D: col=lane&15, row=(lane>>4)*4+reg  [m89/m91]
    #pragma unroll
    for (int r = 0; r < 4; ++r)
        dst[(m0 + r0 + r) * ldc + c0 + col] = acc[r];
}

// ---------------- kernel 3: fused z_init + rel_feat writer (round-5 structure) ----------------
__launch_bounds__(256)
__global__ void fused_z_rel_kernel(const float* __restrict__ a_in, const float* __restrict__ b_in,
                                   const unsigned short* __restrict__ wpt_g,
                                   const float* __restrict__ wbond, const float* __restrict__ contact,
                                   const int* __restrict__ tok, const int* __restrict__ res,
                                   const int* __restrict__ asym, const int* __restrict__ ent,
                                   const int* __restrict__ sym,
                                   float* __restrict__ z_out, float* __restrict__ rel_out) {
    __shared__ int   pkS[256];
    __shared__ float cfS[256];

    int tid = threadIdx.x;
    int i   = blockIdx.x;
    int j0  = blockIdx.y * 256;
    int c    = (tid & 31) * 4;
    int jrow = tid >> 5;

    // per-lane constants (global, L2-hit)
    f32x4 av  = *reinterpret_cast<const f32x4*>(&a_in[i * CZ + c]);
    f32x4 wbv = *reinterpret_cast<const f32x4*>(&wbond[c]);
    u32x2 us  = *reinterpret_cast<const u32x2*>(&wpt_g[132 * CZ + c]);

    pkS[tid] = make_pk(i, j0 + tid, tok, res, asym, ent, sym);
    cfS[tid] = contact[i * NTOK + j0 + tid];
    __syncthreads();

    float wse0 = bf_lo(us.x), wse1 = bf_hi(us.x), wse2 = bf_lo(us.y), wse3 = bf_hi(us.y);
    size_t zbase = ((size_t)(i * NTOK + j0)) * CZ;

    #pragma unroll 4
    for (int it = 0; it < 32; ++it) {
        int jj = jrow + it * 8;
        int pk = pkS[jj];
        float cf = cfS[jj];
        float pse = (float)((unsigned)pk >> 24);
        int p1 = (pk & 255) * CZ + c;
        int p2 = ((pk >> 8) & 255) * CZ + c;
        int p3 = ((pk >> 16) & 255) * CZ + c;
        f32x4 bv = *reinterpret_cast<const f32x4*>(&b_in[(j0 + jj) * CZ + c]);
        u32x2 u1 = *reinterpret_cast<const u32x2*>(&wpt_g[p1]);
        u32x2 u2 = *reinterpret_cast<const u32x2*>(&wpt_g[p2]);
        u32x2 u3 = *reinterpret_cast<const u32x2*>(&wpt_g[p3]);
        f32x4 z;
        z.x = av.x + bv.x + bf_lo(u1.x) + bf_lo(u2.x) + bf_lo(u3.x) + pse * wse0 + cf * wbv.x;
        z.y = av.y + bv.y + bf_hi(u1.x) + bf_hi(u2.x) + bf_hi(u3.x) + pse * wse1 + cf * wbv.y;
        z.z = av.z + bv.z + bf_lo(u1.y) + bf_lo(u2.y) + bf_lo(u3.y) + pse * wse2 + cf * wbv.z;
        z.w = av.w + bv.w + bf_hi(u1.y) + bf_hi(u2.y) + bf_hi(u3.y) + pse * wse3 + cf * wbv.w;
        *reinterpret_cast<f32x4*>(&z_out[zbase + (size_t)(jj * CZ + c)]) = z;
    }

    // rel: 256*139 = 35584 floats = 8896 aligned f32x4, flat stream.
    size_t rbase = ((size_t)(i * NTOK + j0)) * RELD;
    for (int f = tid; f < (256 * RELD) / 4; f += 256) {
        int e = f * 4;
        float v[4];
        #pragma unroll
        for (int k = 0; k < 4; ++k) {
            int ek = e + k;
            // exact j = ek/139 for ek < 35584:  (ek*482798) >> 26, via umulhi(ek<<6, M)
            int j = (int)__umulhi((unsigned)(ek << 6), 482798u);
            int r = ek - j * 139;
            int pk = pkS[j];
            int hit = (r == (pk & 255)) | (r == ((pk >> 8) & 255)) | (r == ((pk >> 16) & 255));
            float pse = (float)((unsigned)pk >> 24);
            v[k] = hit ? 1.0f : ((r == 132) ? pse : 0.0f);
        }
        f32x4 vv = {v[0], v[1], v[2], v[3]};
        *reinterpret_cast<f32x4*>(&rel_out[rbase + (size_t)e]) = vv;
    }
}

// ---------------- launcher ----------------
extern "C" void kernel_launch(void* const* d_in, const int* in_sizes, int n_in,
                              void* d_out, int out_size, void* d_ws, size_t ws_size,
                              hipStream_t stream) {
    const float* tf      = (const float*)d_in[0];
    const float* ta      = (const float*)d_in[1];
    const float* contact = (const float*)d_in[2];
    const int*   tok     = (const int*)d_in[3];
    const int*   res     = (const int*)d_in[4];
    const int*   asym    = (const int*)d_in[5];
    const int*   ent     = (const int*)d_in[6];
    const int*   sym     = (const int*)d_in[7];
    const float* Wsingle = (const float*)d_in[8];
    const float* Wleft   = (const float*)d_in[9];
    const float* Wright  = (const float*)d_in[10];
    const float* Wpos    = (const float*)d_in[11];
    const float* Wbond   = (const float*)d_in[12];

    float* out     = (float*)d_out;
    float* s_input = out;
    float* s_init  = out + OFF_SINIT;
    float* z       = out + OFF_Z;
    float* rel     = out + OFF_REL;

    char* wsb = (char*)d_ws;
    float*          a_ws = (float*)(wsb + WSB_A);
    float*          b_ws = (float*)(wsb + WSB_B);
    unsigned short* wpt  = (unsigned short*)(wsb + WSB_WPT);
    short*          Sb   = (short*)(wsb + WSB_SB);
    short*          Wb   = (short*)(wsb + WSB_WB);

    prep_kernel<<<(PREP_TOTAL + 255) / 256, 256, 0, stream>>>(
        tf, ta, Wsingle, Wleft, Wright, Wpos, s_input, Sb, Wb, wpt);

    mfma_gemm_kernel<<<dim3(48, 10), 256, 0, stream>>>(Sb, Wb, s_init, a_ws, b_ws);

    fused_z_rel_kernel<<<dim3(768, 3), 256, 0, stream>>>(
        a_ws, b_ws, wpt, Wbond, contact, tok, res, asym, ent, sym, z, rel);
}